// Round 1
// baseline (898.082 us; speedup 1.0000x reference)
//
#include <hip/hip_runtime.h>
#include <hip/hip_bf16.h>

// Problem constants (fixed by setup_inputs)
#define N_INST 524288
#define NF     256
#define LDIM   128
#define NBAGS  4096
#define BM     64      // rows per block (halved: kills the 420 B/thread spill)

typedef __attribute__((ext_vector_type(8)))  short          short8;
typedef __attribute__((ext_vector_type(16))) float          f32x16;
typedef __attribute__((ext_vector_type(4)))  unsigned short ushort4v;
typedef __attribute__((ext_vector_type(4)))  int            int4v;

__device__ __forceinline__ unsigned short f2bf(float f) {
    unsigned u = __float_as_uint(f);
    unsigned r = u + 0x7FFFu + ((u >> 16) & 1u);   // round-to-nearest-even
    return (unsigned short)(r >> 16);
}

// ---------------------------------------------------------------------------
// Kernel 0: pack B̂ = [W_V | W_U] into MFMA B-fragment order:
// Bws[ks(16)][ct(8)][lane(64)][j(8)] bf16.
// ct = cg*2 + vu ; n = (ct>>1)*32 + (lane&31) ; k = ks*16 + (lane>>5)*8 + j
// ---------------------------------------------------------------------------
__global__ __launch_bounds__(256) void k_build(const float* __restrict__ W_V,
                                               const float* __restrict__ W_U,
                                               unsigned short* __restrict__ Bws) {
    int idx  = blockIdx.x * 256 + threadIdx.x;       // 0..65535
    int j    = idx & 7;
    int lane = (idx >> 3) & 63;
    int ct   = (idx >> 9) & 7;
    int ks   = idx >> 12;
    int k    = ks * 16 + ((lane >> 5) << 3) + j;
    int n    = ((ct >> 1) << 5) + (lane & 31);
    const float* src = (ct & 1) ? W_U : W_V;
    Bws[idx] = f2bf(src[k * LDIM + n]);
}

// ---------------------------------------------------------------------------
// Kernel 1: exclusive prefix-scan of split_sizes -> offs[0..NBAGS]
// ---------------------------------------------------------------------------
__global__ __launch_bounds__(256) void k_scan(const int* __restrict__ sraw,
                                              int* __restrict__ offs) {
    __shared__ int csum[256];
    __shared__ int cpref[256];
    const int t = threadIdx.x;
    const bool is64 = (sraw[1] == 0);
    int local[16];
    int ssum = 0;
    for (int j = 0; j < 16; ++j) {
        int i = t * 16 + j;
        int v = is64 ? sraw[2 * i] : sraw[i];
        local[j] = v;
        ssum += v;
    }
    csum[t] = ssum;
    __syncthreads();
    if (t == 0) {
        int run = 0;
        for (int i = 0; i < 256; ++i) { cpref[i] = run; run += csum[i]; }
    }
    __syncthreads();
    int run = cpref[t];
    for (int j = 0; j < 16; ++j) { offs[t * 16 + j] = run; run += local[j]; }
    if (t == 255) offs[NBAGS] = run;
}

// ---------------------------------------------------------------------------
// Kernel 2: fused GEMM, BM=64 rows/block, BN=256 (V128|U128), BK=16, 16 iters.
//  * A staged through double-buffered LDS (depth-2 register prefetch).
//  * B-fragments loaded DIRECTLY from L2-resident Bws (already in frag order)
//    -> no B staging, no B LDS, fewer regs.
//  * 4 accumulators/thread (64 VGPRs) instead of 8 -> fits 170-reg cap at
//    3 waves/SIMD with zero scratch.
// ---------------------------------------------------------------------------
__global__ __launch_bounds__(256, 3) void k_gemm(
    const float* __restrict__ feats, const unsigned short* __restrict__ Bws,
    const float* __restrict__ W_ins, const float* __restrict__ b_ins,
    const float* __restrict__ b_V,   const float* __restrict__ b_U,
    const float* __restrict__ w_att, const float* __restrict__ b_att,
    float* __restrict__ scores, float* __restrict__ inst_out) {

    __shared__ unsigned short Al[2][1024];   // [buf][rt(2)][khalf(2)][row32][8]
    __shared__ float winsl[NF];
    __shared__ float bVl[LDIM], bUl[LDIM], wal[LDIM];
    __shared__ float Sp[BM][4];

    const int t    = threadIdx.x;
    const int lane = t & 63;
    const int cg   = t >> 6;              // wave id == col group (0..3)
    const long r0  = (long)blockIdx.x * BM;

    // staging: each thread owns (row = t>>2, k-quarter q = t&3)
    const int row = t >> 2;               // 0..63
    const int q   = t & 3;

    winsl[t] = W_ins[t];
    if (t < LDIM) { bVl[t] = b_V[t]; bUl[t] = b_U[t]; wal[t] = w_att[t]; }

    const float*  arow = feats + (r0 + row) * NF + q * 4;
    const short8* bw   = (const short8*)Bws;   // index: (ks*8+ct)*64 + lane

    const int aoff = ((row >> 5) * 64 + (q >> 1) * 32 + (row & 31)) * 8 + (q & 1) * 4;
    const int ctv  = cg * 2;
    const int ctu  = ctv + 1;

    // ---- depth-2 prefetch prologue (issued before the preamble barrier) ----
    float4 pa_0  = *(const float4*)(arow);
    short8 fbv_0 = bw[(0 * 8 + ctv) * 64 + lane];
    short8 fbu_0 = bw[(0 * 8 + ctu) * 64 + lane];
    float4 pa_1  = *(const float4*)(arow + 16);
    short8 fbv_1 = bw[(1 * 8 + ctv) * 64 + lane];
    short8 fbu_1 = bw[(1 * 8 + ctu) * 64 + lane];

    f32x16 accV0 = {}, accV1 = {};
    f32x16 accU0 = {}, accU1 = {};
    float pacc = 0.f;

    __syncthreads();   // winsl/bias visible

    #pragma unroll
    for (int ks = 0; ks < 16; ++ks) {
        const int X = ks & 1;
        // select prefetch register set (compile-time after full unroll)
        float4 av  = X ? pa_1  : pa_0;
        short8 fbv = X ? fbv_1 : fbv_0;
        short8 fbu = X ? fbu_1 : fbu_0;

        // instance-head fp32 dot on the staged quarter
        float4 wv = *(const float4*)&winsl[ks * 16 + q * 4];
        pacc += av.x * wv.x + av.y * wv.y + av.z * wv.z + av.w * wv.w;

        // convert + stage A into LDS buffer X
        ushort4v c;
        c.x = f2bf(av.x); c.y = f2bf(av.y); c.z = f2bf(av.z); c.w = f2bf(av.w);
        *(ushort4v*)&Al[X][aoff] = c;

        // issue loads for ks+2 into the just-freed register set
        if (ks < 14) {
            if (X == 0) {
                pa_0  = *(const float4*)(arow + (ks + 2) * 16);
                fbv_0 = bw[((ks + 2) * 8 + ctv) * 64 + lane];
                fbu_0 = bw[((ks + 2) * 8 + ctu) * 64 + lane];
            } else {
                pa_1  = *(const float4*)(arow + (ks + 2) * 16);
                fbv_1 = bw[((ks + 2) * 8 + ctv) * 64 + lane];
                fbu_1 = bw[((ks + 2) * 8 + ctu) * 64 + lane];
            }
        }

        __syncthreads();   // buffer X fully staged

        short8 fa0 = *(const short8*)&Al[X][(0 * 64 + lane) * 8];
        short8 fa1 = *(const short8*)&Al[X][(1 * 64 + lane) * 8];
        accV0 = __builtin_amdgcn_mfma_f32_32x32x16_bf16(fa0, fbv, accV0, 0, 0, 0);
        accU0 = __builtin_amdgcn_mfma_f32_32x32x16_bf16(fa0, fbu, accU0, 0, 0, 0);
        accV1 = __builtin_amdgcn_mfma_f32_32x32x16_bf16(fa1, fbv, accV1, 0, 0, 0);
        accU1 = __builtin_amdgcn_mfma_f32_32x32x16_bf16(fa1, fbu, accU1, 0, 0, 0);
    }

    // ---- epilogue: gated-attention scores ---------------------------------
    // C/D layout: col = lane&31, row = (reg&3) + 8*(reg>>2) + 4*(lane>>5)
    const int   c32 = lane & 31;
    const int   nn  = cg * 32 + c32;
    const float bv0s = bVl[nn], bu0s = bUl[nn], wn = wal[nn];
    const int   rh  = lane >> 5;

#define EPILOG(RT, AV, AU)                                                    \
    {                                                                         \
        _Pragma("unroll")                                                     \
        for (int r = 0; r < 16; ++r) {                                        \
            float v  = AV[r] + bv0s;                                          \
            float u  = AU[r] + bu0s;                                          \
            float ev = __expf(2.f * v);                                       \
            float th = 1.f - 2.f * __builtin_amdgcn_rcpf(ev + 1.f);           \
            float sg = __builtin_amdgcn_rcpf(1.f + __expf(-u));               \
            float x  = th * sg * wn;                                          \
            x += __shfl_xor(x, 1);                                            \
            x += __shfl_xor(x, 2);                                            \
            x += __shfl_xor(x, 4);                                            \
            x += __shfl_xor(x, 8);                                            \
            x += __shfl_xor(x, 16);                                           \
            if (c32 == 0)                                                     \
                Sp[RT * 32 + (r & 3) + 8 * (r >> 2) + 4 * rh][cg] = x;        \
        }                                                                     \
    }
    EPILOG(0, accV0, accU0)
    EPILOG(1, accV1, accU1)
#undef EPILOG

    // ---- inst_pred (exact fp32): combine 4 quarter-partials per row -------
    float pt = pacc;
    pt += __shfl_xor(pt, 1);
    pt += __shfl_xor(pt, 2);
    if (q == 0) inst_out[r0 + row] = pt + b_ins[0];

    __syncthreads();
    if (t < BM)
        scores[r0 + t] = Sp[t][0] + Sp[t][1] + Sp[t][2] + Sp[t][3] + b_att[0];
}

// ---------------------------------------------------------------------------
// Kernel 3: per-bag softmax + weighted sum. One wave per bag.
// ---------------------------------------------------------------------------
__global__ __launch_bounds__(64) void k_bags(const int* __restrict__ offs,
                                             const float* __restrict__ scores,
                                             const float* __restrict__ inst,
                                             float* __restrict__ bag_out) {
    const int b    = blockIdx.x;
    const int lane = threadIdx.x;
    const int s0 = offs[b], s1 = offs[b + 1];
    float m = -1e30f;
    for (int i = s0 + lane; i < s1; i += 64) m = fmaxf(m, scores[i]);
    #pragma unroll
    for (int d = 32; d; d >>= 1) m = fmaxf(m, __shfl_xor(m, d));
    float se = 0.f, sp = 0.f;
    for (int i = s0 + lane; i < s1; i += 64) {
        float e = __expf(scores[i] - m);
        se += e;
        sp += e * inst[i];
    }
    #pragma unroll
    for (int d = 32; d; d >>= 1) { se += __shfl_xor(se, d); sp += __shfl_xor(sp, d); }
    if (lane == 0) bag_out[b] = sp / se;
}

// ---------------------------------------------------------------------------
extern "C" void kernel_launch(void* const* d_in, const int* in_sizes, int n_in,
                              void* d_out, int out_size, void* d_ws, size_t ws_size,
                              hipStream_t stream) {
    const float* feats  = (const float*)d_in[0];
    const int*   sizesr = (const int*)d_in[1];   // int64 or int32, probed in-kernel
    const float* W_ins  = (const float*)d_in[2];
    const float* b_ins  = (const float*)d_in[3];
    const float* W_V    = (const float*)d_in[4];
    const float* b_V    = (const float*)d_in[5];
    const float* W_U    = (const float*)d_in[6];
    const float* b_U    = (const float*)d_in[7];
    const float* w_att  = (const float*)d_in[8];
    const float* b_att  = (const float*)d_in[9];

    // ws layout: [0,128K) Bws bf16 | [128K,+16K) offs | [160K, 160K+2M) scores
    unsigned short* Bws    = (unsigned short*)d_ws;
    int*            offs   = (int*)((char*)d_ws + (128 << 10));
    float*          scores = (float*)((char*)d_ws + (160 << 10));

    float* bag_out  = (float*)d_out;
    float* inst_out = (float*)d_out + NBAGS;

    hipLaunchKernelGGL(k_build, dim3(256), dim3(256), 0, stream, W_V, W_U, Bws);
    hipLaunchKernelGGL(k_scan,  dim3(1),   dim3(256), 0, stream, sizesr, offs);
    hipLaunchKernelGGL(k_gemm,  dim3(N_INST / BM), dim3(256), 0, stream,
                       feats, Bws, W_ins, b_ins, b_V, b_U, w_att, b_att,
                       scores, inst_out);
    hipLaunchKernelGGL(k_bags,  dim3(NBAGS), dim3(64), 0, stream,
                       offs, scores, inst_out, bag_out);
}